// Round 3
// baseline (107.913 us; speedup 1.0000x reference)
//
#include <hip/hip_runtime.h>
#include <stdint.h>

#define BB    4
#define CC    320
#define HH    135
#define WW    240
#define HW    (HH*WW)      // 32400
#define PNUM  12960
#define NBUCK 16384
#define MAXPER 32
#define NCH   4            // channels per thread in k_apply
#define PIX   8            // pixels per thread in k_apply
#define P8    (HW/PIX)     // 4050
#define NTILE ((CC/NCH)*P8) // 324000 threads

typedef float f4 __attribute__((ext_vector_type(4)));
typedef unsigned u4 __attribute__((ext_vector_type(4)));

// ---- Pass 1: bucket each pixel by value, record bucket members ----
__global__ __launch_bounds__(256) void k_bucket(const float* __restrict__ unc,
                                                unsigned* __restrict__ hist,
                                                unsigned* __restrict__ members) {
    int i = blockIdx.x * 256 + threadIdx.x;
    if (i >= HW) return;
    float v = unc[i];
    int b = (int)(v * (float)NBUCK);          // monotonic in v; equal v -> same bucket
    b = b < 0 ? 0 : (b > NBUCK - 1 ? NBUCK - 1 : b);
    unsigned pos = atomicAdd(&hist[b], 1u);
    if (pos < MAXPER) members[(unsigned)b * MAXPER + pos] = (unsigned)i;
}

// ---- Pass 2: base[b] = # elements in buckets strictly greater than b ----
__global__ __launch_bounds__(1024) void k_scan(const unsigned* __restrict__ hist,
                                               unsigned* __restrict__ base) {
    __shared__ unsigned sh[1024];
    const int CH = NBUCK / 1024;  // 16
    int t = threadIdx.x;
    unsigned loc[CH];
    unsigned s = 0;
    #pragma unroll
    for (int k = 0; k < CH; ++k) { loc[k] = hist[t * CH + k]; s += loc[k]; }
    sh[t] = s;
    __syncthreads();
    for (int off = 1; off < 1024; off <<= 1) {
        unsigned v = (t + off < 1024) ? sh[t + off] : 0u;
        __syncthreads();
        sh[t] += v;
        __syncthreads();
    }
    unsigned run = sh[t] - s;   // exclusive suffix: everything in higher chunks
    #pragma unroll
    for (int k = CH - 1; k >= 0; --k) { base[t * CH + k] = run; run += loc[k]; }
}

// ---- Pass 3: exact descending rank with (value desc, index asc) tie-break ----
__global__ __launch_bounds__(256) void k_rank(const float* __restrict__ unc,
                                              const unsigned* __restrict__ hist,
                                              const unsigned* __restrict__ base,
                                              const unsigned* __restrict__ members,
                                              unsigned* __restrict__ rank) {
    int i = blockIdx.x * 256 + threadIdx.x;
    if (i >= HW) return;
    float vi = unc[i];
    int b = (int)(vi * (float)NBUCK);
    b = b < 0 ? 0 : (b > NBUCK - 1 ? NBUCK - 1 : b);
    unsigned cnt = hist[b];
    if (cnt > MAXPER) cnt = MAXPER;
    unsigned r = base[b];
    for (unsigned k = 0; k < cnt; ++k) {
        unsigned j = members[(unsigned)b * MAXPER + k];
        if (j == (unsigned)i) continue;
        float vj = unc[j];
        r += (vj > vi) || (vj == vi && j < (unsigned)i);
    }
    rank[i] = r;
}

// ---- Pass 4: out = x + scatter(prompts) ----
// Thread tile: 4 consecutive channels x 8 consecutive pixels x all 4 batches.
// All 8 prompt gathers (16B each, fully used) issued up front; 32 streaming
// load-add-store iterations give the scheduler plenty of independent VMEM ops.
// Plain loads on x (L2-assisted); NT stores on out (write-once, don't pollute L2).
__global__ __launch_bounds__(256) void k_apply(const float* __restrict__ x,
                                               const float* __restrict__ prompts,
                                               const unsigned* __restrict__ rank,
                                               float* __restrict__ out) {
    int t = blockIdx.x * 256 + threadIdx.x;
    if (t >= NTILE) return;
    int cg = t / P8;
    int p8 = t - cg * P8;
    int c0 = cg * NCH;
    int p  = p8 * PIX;

    u4 r4a = *(const u4*)(rank + p);
    u4 r4b = *(const u4*)(rank + p + 4);

    // Gather one float4 prompt-row slice per active pixel (reused over 4 batches).
    float g[PIX][NCH];
    #pragma unroll
    for (int k = 0; k < PIX; ++k) {
        unsigned r = (k < 4) ? r4a[k] : r4b[k - 4];
        f4 gv = (f4)(0.0f);
        if (r < PNUM) gv = *(const f4*)(prompts + (size_t)r * CC + c0);
        #pragma unroll
        for (int j = 0; j < NCH; ++j) g[k][j] = gv[j];
    }

    #pragma unroll
    for (int b = 0; b < BB; ++b) {
        #pragma unroll
        for (int j = 0; j < NCH; ++j) {
            int off = (b * CC + c0 + j) * HW + p;
            f4 xv0 = *(const f4*)(x + off);
            f4 xv1 = *(const f4*)(x + off + 4);
            xv0[0] += g[0][j]; xv0[1] += g[1][j]; xv0[2] += g[2][j]; xv0[3] += g[3][j];
            xv1[0] += g[4][j]; xv1[1] += g[5][j]; xv1[2] += g[6][j]; xv1[3] += g[7][j];
            __builtin_nontemporal_store(xv0, (f4*)(out + off));
            __builtin_nontemporal_store(xv1, (f4*)(out + off + 4));
        }
    }
}

extern "C" void kernel_launch(void* const* d_in, const int* in_sizes, int n_in,
                              void* d_out, int out_size, void* d_ws, size_t ws_size,
                              hipStream_t stream) {
    const float* x       = (const float*)d_in[0];
    const float* unc     = (const float*)d_in[1];
    const float* prompts = (const float*)d_in[2];
    float* out = (float*)d_out;

    char* ws = (char*)d_ws;
    unsigned* hist    = (unsigned*)(ws);
    unsigned* base    = (unsigned*)(ws + (size_t)NBUCK * 4);
    unsigned* members = (unsigned*)(ws + (size_t)NBUCK * 8);
    unsigned* rank    = (unsigned*)(ws + (size_t)NBUCK * 8 + (size_t)NBUCK * MAXPER * 4);

    hipMemsetAsync(hist, 0, (size_t)NBUCK * 4, stream);
    k_bucket<<<(HW + 255) / 256, 256, 0, stream>>>(unc, hist, members);
    k_scan<<<1, 1024, 0, stream>>>(hist, base);
    k_rank<<<(HW + 255) / 256, 256, 0, stream>>>(unc, hist, base, members, rank);
    k_apply<<<(NTILE + 255) / 256, 256, 0, stream>>>(x, prompts, rank, out);
}

// Round 4
// 88.554 us; speedup vs baseline: 1.2186x; 1.2186x over previous
//
#include <hip/hip_runtime.h>
#include <stdint.h>

#define BB    4
#define CC    320
#define HH    135
#define WW    240
#define HW    (HH*WW)      // 32400
#define PNUM  12960
#define NBUCK 16384
#define MAXPER 32
#define P4    (HW/4)       // 8100
#define NCH   4            // channels per thread in k_apply
#define NTILE ((CC/NCH)*P4) // 648000 threads

typedef float f4 __attribute__((ext_vector_type(4)));
typedef unsigned u4 __attribute__((ext_vector_type(4)));

// ---- Pass 0: zero the histogram (replaces hipMemsetAsync) ----
__global__ __launch_bounds__(256) void k_zero(unsigned* __restrict__ hist) {
    int i = blockIdx.x * 256 + threadIdx.x;
    if (i < NBUCK) hist[i] = 0u;
}

// ---- Pass 1: bucket each pixel by value, record bucket members ----
__global__ __launch_bounds__(256) void k_bucket(const float* __restrict__ unc,
                                                unsigned* __restrict__ hist,
                                                unsigned* __restrict__ members) {
    int i = blockIdx.x * 256 + threadIdx.x;
    if (i >= HW) return;
    float v = unc[i];
    int b = (int)(v * (float)NBUCK);          // monotonic in v; equal v -> same bucket
    b = b < 0 ? 0 : (b > NBUCK - 1 ? NBUCK - 1 : b);
    unsigned pos = atomicAdd(&hist[b], 1u);
    if (pos < MAXPER) members[(unsigned)b * MAXPER + pos] = (unsigned)i;
}

// ---- Pass 2: base[b] = # elements in buckets strictly greater than b ----
__global__ __launch_bounds__(1024) void k_scan(const unsigned* __restrict__ hist,
                                               unsigned* __restrict__ base) {
    __shared__ unsigned sh[1024];
    const int CH = NBUCK / 1024;  // 16
    int t = threadIdx.x;
    unsigned loc[CH];
    unsigned s = 0;
    #pragma unroll
    for (int k = 0; k < CH; ++k) { loc[k] = hist[t * CH + k]; s += loc[k]; }
    sh[t] = s;
    __syncthreads();
    for (int off = 1; off < 1024; off <<= 1) {
        unsigned v = (t + off < 1024) ? sh[t + off] : 0u;
        __syncthreads();
        sh[t] += v;
        __syncthreads();
    }
    unsigned run = sh[t] - s;   // exclusive suffix: everything in higher chunks
    #pragma unroll
    for (int k = CH - 1; k >= 0; --k) { base[t * CH + k] = run; run += loc[k]; }
}

// ---- Pass 3: exact descending rank with (value desc, index asc) tie-break ----
__global__ __launch_bounds__(256) void k_rank(const float* __restrict__ unc,
                                              const unsigned* __restrict__ hist,
                                              const unsigned* __restrict__ base,
                                              const unsigned* __restrict__ members,
                                              unsigned* __restrict__ rank) {
    int i = blockIdx.x * 256 + threadIdx.x;
    if (i >= HW) return;
    float vi = unc[i];
    int b = (int)(vi * (float)NBUCK);
    b = b < 0 ? 0 : (b > NBUCK - 1 ? NBUCK - 1 : b);
    unsigned cnt = hist[b];
    if (cnt > MAXPER) cnt = MAXPER;
    unsigned r = base[b];
    for (unsigned k = 0; k < cnt; ++k) {
        unsigned j = members[(unsigned)b * MAXPER + k];
        if (j == (unsigned)i) continue;
        float vj = unc[j];
        r += (vj > vi) || (vj == vi && j < (unsigned)i);
    }
    rank[i] = r;
}

// ---- Pass 4: out = x + scatter(prompts) ----
// R2-proven config: 4 channels x 4 pixels x 4 batches per thread, 648k threads
// (10128 waves -> machine full), NT loads+stores. New: explicit 2-deep software
// pipeline in the streaming loop so >=2 x-loads stay in flight per thread.
#define OFFS(it) ((((it) >> 2) * CC + c0 + ((it) & 3)) * HW + p)
__global__ __launch_bounds__(256) void k_apply(const float* __restrict__ x,
                                               const float* __restrict__ prompts,
                                               const unsigned* __restrict__ rank,
                                               float* __restrict__ out) {
    int t = blockIdx.x * 256 + threadIdx.x;
    if (t >= NTILE) return;
    int cg = t / P4;
    int p4 = t - cg * P4;
    int c0 = cg * NCH;
    int p  = p4 * 4;

    u4 r4 = *(const u4*)(rank + p);

    // Gather one float4 prompt-row slice per active pixel (reused over 4 batches).
    float g[4][NCH];
    #pragma unroll
    for (int k = 0; k < 4; ++k) {
        unsigned r = r4[k];
        f4 gv = (f4)(0.0f);
        if (r < PNUM) gv = *(const f4*)(prompts + (size_t)r * CC + c0);
        #pragma unroll
        for (int j = 0; j < NCH; ++j) g[k][j] = gv[j];
    }

    // 16 streaming iterations (b = it>>2, j = it&3), 2-deep pipeline.
    f4 a  = __builtin_nontemporal_load((const f4*)(x + OFFS(0)));
    f4 bv = __builtin_nontemporal_load((const f4*)(x + OFFS(1)));
    #pragma unroll
    for (int it = 0; it < 16; ++it) {
        f4 c = (f4)(0.0f);
        if (it < 14) c = __builtin_nontemporal_load((const f4*)(x + OFFS(it + 2)));
        int j = it & 3;
        a[0] += g[0][j]; a[1] += g[1][j]; a[2] += g[2][j]; a[3] += g[3][j];
        __builtin_nontemporal_store(a, (f4*)(out + OFFS(it)));
        a = bv; bv = c;
    }
}

extern "C" void kernel_launch(void* const* d_in, const int* in_sizes, int n_in,
                              void* d_out, int out_size, void* d_ws, size_t ws_size,
                              hipStream_t stream) {
    const float* x       = (const float*)d_in[0];
    const float* unc     = (const float*)d_in[1];
    const float* prompts = (const float*)d_in[2];
    float* out = (float*)d_out;

    char* ws = (char*)d_ws;
    unsigned* hist    = (unsigned*)(ws);
    unsigned* base    = (unsigned*)(ws + (size_t)NBUCK * 4);
    unsigned* members = (unsigned*)(ws + (size_t)NBUCK * 8);
    unsigned* rank    = (unsigned*)(ws + (size_t)NBUCK * 8 + (size_t)NBUCK * MAXPER * 4);

    k_zero<<<NBUCK / 256, 256, 0, stream>>>(hist);
    k_bucket<<<(HW + 255) / 256, 256, 0, stream>>>(unc, hist, members);
    k_scan<<<1, 1024, 0, stream>>>(hist, base);
    k_rank<<<(HW + 255) / 256, 256, 0, stream>>>(unc, hist, base, members, rank);
    k_apply<<<(NTILE + 255) / 256, 256, 0, stream>>>(x, prompts, rank, out);
}